// Round 1
// baseline (2075.283 us; speedup 1.0000x reference)
//
#include <hip/hip_runtime.h>

#define DIM 128

// ---------------------------------------------------------------------------
// K1: per-row inverse L2 norm for both embedding tables.
// One 64-lane wave per row; lane holds float2 (128 dims).
// ---------------------------------------------------------------------------
__global__ __launch_bounds__(256)
void k_invlen(const float* __restrict__ user_emb, const float* __restrict__ item_emb,
              float* __restrict__ invlen_u, float* __restrict__ invlen_i,
              int n_u, int n_i) {
    const int wave = (blockIdx.x * blockDim.x + threadIdx.x) >> 6;
    const int lane = threadIdx.x & 63;
    const int total = n_u + n_i;
    if (wave >= total) return;
    const float* src;
    float* dst;
    int row;
    if (wave < n_u) { src = user_emb; dst = invlen_u; row = wave; }
    else            { src = item_emb; dst = invlen_i; row = wave - n_u; }
    const float2 v = *reinterpret_cast<const float2*>(src + (size_t)row * DIM + lane * 2);
    float s = v.x * v.x + v.y * v.y;
    #pragma unroll
    for (int off = 32; off >= 1; off >>= 1) s += __shfl_xor(s, off);
    if (lane == 0) dst[row] = rsqrtf(s);
}

// ---------------------------------------------------------------------------
// K2: scatter normalized src rows into S[dst] and count degrees.
// One wave per edge; handles BOTH directions (u->i and i->u).
// S_item[i] += user_emb[u]*invlen_u[u];  S_user[u] += item_emb[i]*invlen_i[i]
// ---------------------------------------------------------------------------
__global__ __launch_bounds__(256)
void k_scatter_S(const float* __restrict__ user_emb, const float* __restrict__ item_emb,
                 const int* __restrict__ eu, const int* __restrict__ ei,
                 const float* __restrict__ invlen_u, const float* __restrict__ invlen_i,
                 float* __restrict__ S_user, float* __restrict__ S_item,
                 float* __restrict__ deg_u, float* __restrict__ deg_i, int E) {
    const int wave = (blockIdx.x * blockDim.x + threadIdx.x) >> 6;
    const int lane = threadIdx.x & 63;
    if (wave >= E) return;
    const int u  = eu[wave];
    const int it = ei[wave];
    const float ilu = invlen_u[u];
    const float ili = invlen_i[it];
    const float2 vu = *reinterpret_cast<const float2*>(user_emb + (size_t)u  * DIM + lane * 2);
    const float2 vi = *reinterpret_cast<const float2*>(item_emb + (size_t)it * DIM + lane * 2);
    float* si = S_item + (size_t)it * DIM + lane * 2;
    float* su = S_user + (size_t)u  * DIM + lane * 2;
    atomicAdd(si,     vu.x * ilu);
    atomicAdd(si + 1, vu.y * ilu);
    atomicAdd(su,     vi.x * ili);
    atomicAdd(su + 1, vi.y * ili);
    if (lane == 0) {
        atomicAdd(deg_i + it, 1.0f);
        atomicAdd(deg_u + u,  1.0f);
    }
}

// ---------------------------------------------------------------------------
// K3: per-edge cosine weight + weighted scatter into outputs.
// w = relu(invlen[src] * dot(emb[src], S[dst])) / max(deg[dst],1)
// out[dst] += w * emb[src]
// ---------------------------------------------------------------------------
__global__ __launch_bounds__(256)
void k_edge_out(const float* __restrict__ user_emb, const float* __restrict__ item_emb,
                const int* __restrict__ eu, const int* __restrict__ ei,
                const float* __restrict__ invlen_u, const float* __restrict__ invlen_i,
                const float* __restrict__ S_user, const float* __restrict__ S_item,
                const float* __restrict__ deg_u, const float* __restrict__ deg_i,
                float* __restrict__ out_user, float* __restrict__ out_item, int E) {
    const int wave = (blockIdx.x * blockDim.x + threadIdx.x) >> 6;
    const int lane = threadIdx.x & 63;
    if (wave >= E) return;
    const int u  = eu[wave];
    const int it = ei[wave];
    const float2 vu = *reinterpret_cast<const float2*>(user_emb + (size_t)u  * DIM + lane * 2);
    const float2 vi = *reinterpret_cast<const float2*>(item_emb + (size_t)it * DIM + lane * 2);
    const float2 si = *reinterpret_cast<const float2*>(S_item + (size_t)it * DIM + lane * 2);
    const float2 su = *reinterpret_cast<const float2*>(S_user + (size_t)u  * DIM + lane * 2);
    float di = vu.x * si.x + vu.y * si.y;   // dot(user_emb[u], S_item[i])
    float du = vi.x * su.x + vi.y * su.y;   // dot(item_emb[i], S_user[u])
    #pragma unroll
    for (int off = 32; off >= 1; off >>= 1) {
        di += __shfl_xor(di, off);
        du += __shfl_xor(du, off);
    }
    const float wi = fmaxf(di * invlen_u[u],  0.0f) / fmaxf(deg_i[it], 1.0f);
    const float wu = fmaxf(du * invlen_i[it], 0.0f) / fmaxf(deg_u[u],  1.0f);
    float* oi = out_item + (size_t)it * DIM + lane * 2;
    float* ou = out_user + (size_t)u  * DIM + lane * 2;
    atomicAdd(oi,     wi * vu.x);
    atomicAdd(oi + 1, wi * vu.y);
    atomicAdd(ou,     wu * vi.x);
    atomicAdd(ou + 1, wu * vi.y);
}

// ---------------------------------------------------------------------------
// K4: final deg^-0.5 scaling. d_out layout: [user_out (n_u x 128) | item_out].
// One thread per float4; row = tid >> 5 (128/4 = 32 float4 per row).
// ---------------------------------------------------------------------------
__global__ __launch_bounds__(256)
void k_scale(float* __restrict__ out, const float* __restrict__ deg_u,
             const float* __restrict__ deg_i, int n_u, int n_i) {
    const long long tid = (long long)blockIdx.x * blockDim.x + threadIdx.x;
    const long long total = (long long)(n_u + n_i) * (DIM / 4);
    if (tid >= total) return;
    const int row = (int)(tid >> 5);
    const float deg = (row < n_u) ? deg_u[row] : deg_i[row - n_u];
    const float s = rsqrtf(fmaxf(deg, 1.0f));
    float4* p = reinterpret_cast<float4*>(out) + tid;
    float4 v = *p;
    v.x *= s; v.y *= s; v.z *= s; v.w *= s;
    *p = v;
}

extern "C" void kernel_launch(void* const* d_in, const int* in_sizes, int n_in,
                              void* d_out, int out_size, void* d_ws, size_t ws_size,
                              hipStream_t stream) {
    const float* user_emb = (const float*)d_in[0];
    const float* item_emb = (const float*)d_in[1];
    const int*   eu       = (const int*)d_in[2];
    const int*   ei       = (const int*)d_in[3];
    const int n_u = in_sizes[0] / DIM;
    const int n_i = in_sizes[1] / DIM;
    const int E   = in_sizes[2];

    // Workspace layout (all f32):
    // [ S_user (n_u*128) | S_item (n_i*128) | deg_u (n_u) | deg_i (n_i)
    //   | invlen_u (n_u) | invlen_i (n_i) ]
    char* ws = (char*)d_ws;
    float* S_user   = (float*)ws; ws += (size_t)n_u * DIM * sizeof(float);
    float* S_item   = (float*)ws; ws += (size_t)n_i * DIM * sizeof(float);
    float* deg_u    = (float*)ws; ws += (size_t)n_u * sizeof(float);
    float* deg_i    = (float*)ws; ws += (size_t)n_i * sizeof(float);
    float* invlen_u = (float*)ws; ws += (size_t)n_u * sizeof(float);
    float* invlen_i = (float*)ws; ws += (size_t)n_i * sizeof(float);

    float* out_user = (float*)d_out;
    float* out_item = out_user + (size_t)n_u * DIM;

    // Zero the accumulators (S + deg) and the output.
    const size_t zero_bytes = ((size_t)(n_u + n_i) * DIM + (size_t)n_u + (size_t)n_i) * sizeof(float);
    hipMemsetAsync(d_ws, 0, zero_bytes, stream);
    hipMemsetAsync(d_out, 0, (size_t)out_size * sizeof(float), stream);

    {   // K1: inverse norms
        const int waves  = n_u + n_i;
        const int blocks = (waves + 3) / 4;   // 4 waves per 256-thread block
        k_invlen<<<blocks, 256, 0, stream>>>(user_emb, item_emb, invlen_u, invlen_i, n_u, n_i);
    }
    {   // K2 + K3: edge passes (one wave per edge)
        const int blocks = (E + 3) / 4;
        k_scatter_S<<<blocks, 256, 0, stream>>>(user_emb, item_emb, eu, ei,
                                                invlen_u, invlen_i,
                                                S_user, S_item, deg_u, deg_i, E);
        k_edge_out<<<blocks, 256, 0, stream>>>(user_emb, item_emb, eu, ei,
                                               invlen_u, invlen_i,
                                               S_user, S_item, deg_u, deg_i,
                                               out_user, out_item, E);
    }
    {   // K4: deg^-0.5 scaling over the whole output
        const long long total  = (long long)(n_u + n_i) * (DIM / 4);
        const int       blocks = (int)((total + 255) / 256);
        k_scale<<<blocks, 256, 0, stream>>>((float*)d_out, deg_u, deg_i, n_u, n_i);
    }
}